// Round 10
// baseline (242.168 us; speedup 1.0000x reference)
//
#include <hip/hip_runtime.h>
#include <hip/hip_fp16.h>
#include <cstdint>

constexpr int BSHIFT = 9;               // 512 nodes per bucket
constexpr int NBUCK  = 256;             // max buckets (covers 131072 nodes)
constexpr int BUCKET_CAP = 6144;        // slot capacity; E/bucket ~ Poisson(5102), 14 sigma
constexpr int BN = 1 << BSHIFT;         // 512

struct alignas(16) H8 { __half2 a, b, c, d; };
struct alignas(8)  H4 { __half2 a, b; };

typedef _Float16 f16x8 __attribute__((ext_vector_type(8)));
typedef float    f32x4 __attribute__((ext_vector_type(4)));

__device__ __forceinline__ float4 add4(float4 a, float4 b) {
    return make_float4(a.x + b.x, a.y + b.y, a.z + b.z, a.w + b.w);
}
__device__ __forceinline__ float4 mul4s(float4 a, float s) {
    return make_float4(a.x * s, a.y * s, a.z * s, a.w * s);
}
__device__ __forceinline__ void acc_h8(float4& A0, float4& A1, const H8 v, float s) {
    float2 f0 = __half22float2(v.a), f1 = __half22float2(v.b);
    float2 f2 = __half22float2(v.c), f3 = __half22float2(v.d);
    A0.x = fmaf(f0.x, s, A0.x); A0.y = fmaf(f0.y, s, A0.y);
    A0.z = fmaf(f1.x, s, A0.z); A0.w = fmaf(f1.y, s, A0.w);
    A1.x = fmaf(f2.x, s, A1.x); A1.y = fmaf(f2.y, s, A1.y);
    A1.z = fmaf(f3.x, s, A1.z); A1.w = fmaf(f3.y, s, A1.w);
}

// ---------------- partition_edges + weight-frag pack (merged) ----------------
// Fragment layout (mfma_f32_16x16x32_f16, B operand): lane l holds
// B[k = kf*32 + (l>>4)*8 + j][m = mt*16 + (l&15)], j=0..7 contiguous.

constexpr int EPT = 16;  // edges per thread; chunk = 4096
__global__ __launch_bounds__(256) void partition_pack(
    const int* __restrict__ src, const int* __restrict__ dst,
    int* __restrict__ bucketCur, int* __restrict__ pairs, int ne, int nEdgeBlocks,
    const float* __restrict__ W1, const float* __restrict__ W2,
    const float* __restrict__ W3,
    __half* __restrict__ P1, __half* __restrict__ P2, __half* __restrict__ P3) {
    if (blockIdx.x == (unsigned)nEdgeBlocks) {
        int t = threadIdx.x;
        for (int i = t; i < 7 * 2 * 64 * 8; i += 256) {      // W1 [64x100] -> 7mt x 2kf
            int j = i & 7, lane = (i >> 3) & 63, f = i >> 9;
            int mt = f >> 1, kf = f & 1;
            int k = kf * 32 + (lane >> 4) * 8 + j;
            int m = mt * 16 + (lane & 15);
            P1[i] = __float2half_rn(m < 100 ? W1[k * 100 + m] : 0.0f);
        }
        for (int i = t; i < 4 * 4 * 64 * 8; i += 256) {      // W2 [100x50] -> [128x64]
            int j = i & 7, lane = (i >> 3) & 63, f = i >> 9;
            int mt = f >> 2, kf = f & 3;
            int k = kf * 32 + (lane >> 4) * 8 + j;
            int m = mt * 16 + (lane & 15);
            P2[i] = __float2half_rn((k < 100 && m < 50) ? W2[k * 50 + m] : 0.0f);
        }
        for (int i = t; i < 2 * 2 * 64 * 8; i += 256) {      // W3 [50x25] -> [64x32]
            int j = i & 7, lane = (i >> 3) & 63, f = i >> 9;
            int mt = f >> 1, kf = f & 1;
            int k = kf * 32 + (lane >> 4) * 8 + j;
            int m = mt * 16 + (lane & 15);
            P3[i] = __float2half_rn((k < 50 && m < 25) ? W3[k * 25 + m] : 0.0f);
        }
        return;
    }
    __shared__ int lcnt[NBUCK];
    __shared__ int lbase[NBUCK];
    int base = blockIdx.x * (256 * EPT);
    if (threadIdx.x < NBUCK) lcnt[threadIdx.x] = 0;
    __syncthreads();
    int2 ed[EPT];
    int  rnk[EPT];
#pragma unroll
    for (int j = 0; j < EPT; ++j) {
        int e = base + j * 256 + threadIdx.x;
        if (e < ne) {
            int d = dst[e];
            ed[j] = make_int2(src[e], d);
            rnk[j] = atomicAdd(&lcnt[d >> BSHIFT], 1);
        } else {
            ed[j].y = -1;
        }
    }
    __syncthreads();
    if (threadIdx.x < NBUCK) {
        int c = lcnt[threadIdx.x];
        lbase[threadIdx.x] = c ? atomicAdd(&bucketCur[threadIdx.x], c) : 0;
    }
    __syncthreads();
#pragma unroll
    for (int j = 0; j < EPT; ++j) {
        if (ed[j].y >= 0) {
            int b = ed[j].y >> BSHIFT;
            int p = lbase[b] + rnk[j];
            if (p < BUCKET_CAP)
                pairs[(size_t)b * BUCKET_CAP + p] =
                    (ed[j].x << BSHIFT) | (ed[j].y & (BN - 1));
        }
    }
}

// ---------------- bucket_csr with internal bucket-base scan (R3-proven) ----------------
__global__ __launch_bounds__(256) void bucket_csr_scan(
    const int* __restrict__ pairs, const int* __restrict__ bucketCnt,
    int* __restrict__ offs, float* __restrict__ dinv, int* __restrict__ csr,
    int n, int ne, int nbuckets) {
    __shared__ int hist[BN];
    __shared__ int cur[BN];
    __shared__ int tmp[256];
    __shared__ int baseS;
    int b = blockIdx.x;
    int t = threadIdx.x;

    int c = (t < (unsigned)nbuckets) ? bucketCnt[t] : 0;
    tmp[t] = c;
    __syncthreads();
    for (int off = 1; off < 256; off <<= 1) {
        int v = (t >= (unsigned)off) ? tmp[t - off] : 0;
        __syncthreads();
        tmp[t] += v;
        __syncthreads();
    }
    if (t == 0) {
        baseS = b ? tmp[b - 1] : 0;
        if (b == 0) offs[n] = ne;
    }
    __syncthreads();
    int base = baseS;
    int cnt  = bucketCnt[b];
    const int* pb = pairs + (size_t)b * BUCKET_CAP;
    int nodeLo = b << BSHIFT;

    hist[t] = 0;
    hist[t + 256] = 0;
    __syncthreads();
    for (int e = t; e < cnt; e += 256)
        atomicAdd(&hist[pb[e] & (BN - 1)], 1);
    __syncthreads();

    int l0 = 2 * t, l1 = l0 + 1;
    int h0 = hist[l0], h1 = hist[l1];
    tmp[t] = h0 + h1;
    __syncthreads();
    for (int off = 1; off < 256; off <<= 1) {
        int v = (t >= (unsigned)off) ? tmp[t - off] : 0;
        __syncthreads();
        tmp[t] += v;
        __syncthreads();
    }
    int e0 = tmp[t] - (h0 + h1);
    int e1 = e0 + h0;
    int g0 = nodeLo + l0, g1 = nodeLo + l1;
    if (g0 < n) { offs[g0] = base + e0; dinv[g0] = rsqrtf((float)(h0 + 1)); }
    if (g1 < n) { offs[g1] = base + e1; dinv[g1] = rsqrtf((float)(h1 + 1)); }
    cur[l0] = e0;
    cur[l1] = e1;
    __syncthreads();

    for (int e = t; e < cnt; e += 256) {
        int p = pb[e];
        int pos = atomicAdd(&cur[p & (BN - 1)], 1);
        csr[base + pos] = ((unsigned)p) >> BSHIFT;
    }
}

// ---------------- fp32 -> fp16 planar convert, prescaled by dinv ----------------
// Planes A/B each [n x 32] halves (6.4MB): halves the gather working set per agg pass.
__global__ void cvt_scale_planar(const float* __restrict__ x, const float* __restrict__ dinv,
                                 __half* __restrict__ oA, __half* __restrict__ oB, int n16) {
    int i = blockIdx.x * blockDim.x + threadIdx.x;
    if (i < n16) {
        int node = i >> 4, c = (i & 15) * 4;
        float dv = dinv[node];
        float4 v = ((const float4*)x)[i];
        H4 h;
        h.a = __floats2half2_rn(v.x * dv, v.y * dv);
        h.b = __floats2half2_rn(v.z * dv, v.w * dv);
        if (c < 32) *(H4*)&oA[(size_t)node * 32 + c] = h;
        else        *(H4*)&oB[(size_t)node * 32 + c - 32] = h;
    }
}

// ---------------- fused agg1 + gemm1 + gemm2 (MFMA), planar gather ----------------
// Block = 64 nodes, 4 waves; wave handles 16 nodes (4 lanes/node, 16B/lane).
// Phase 0 runs TWO plane-passes (cols 0-31 then 32-63): device-wide working set
// 6.4MB per pass -> fits per-XCD L2 better than the 12.8MB interleaved layout.
constexpr int XSP = 72;   // Xs row stride, halves (144B = 16B-aligned)
constexpr int HPS = 136;  // Hs row stride, halves (272B = 16B-aligned)
__global__ __launch_bounds__(256, 4) void agg1gemm12(
    const __half* __restrict__ xA, const __half* __restrict__ xB,
    const int* __restrict__ offs, const int* __restrict__ csr,
    const float* __restrict__ dinv,
    const __half* __restrict__ P1, const float* __restrict__ b1,
    const __half* __restrict__ P2,
    __half* __restrict__ outA, __half* __restrict__ outB, int n) {
    __shared__ alignas(16) _Float16 Xs[64 * XSP];   // 9.2 KB (agg out, then D staging)
    __shared__ alignas(16) _Float16 Hs[64 * HPS];   // 17.4 KB
    int tid = threadIdx.x, lane = tid & 63, w = tid >> 6;
    int lg = lane >> 4, lr = lane & 15;
    int blockBase = blockIdx.x * 64;

    // zero Hs pad cols 112..127 (read by W2 kfrag3; must be finite)
    for (int i = tid; i < 64 * 2; i += 256) {
        f16x8 zz = {};
        *(f16x8*)&Hs[(i >> 1) * HPS + 112 + (i & 1) * 8] = zz;
    }

    // ---- phase 0: two plane-passes, 16 nodes/wave, 4 lanes/node ----
    int nodeL = w * 16 + (lane >> 2);
    int f0 = (lane & 3) * 8;           // cols within plane
    int node = blockBase + nodeL;
#pragma unroll
    for (int pl = 0; pl < 2; ++pl) {
        const __half* xp = pl ? xB : xA;
        float4 z4 = make_float4(0.f, 0.f, 0.f, 0.f);
        float4 a00 = z4, a01 = z4, a10 = z4, a11 = z4, a20 = z4, a21 = z4, a30 = z4, a31 = z4;
        float dv = 0.0f;
        if (node < n) {
            dv = dinv[node];
            H8 sv = *(const H8*)&xp[(size_t)node * 32 + f0];   // self term (prescaled)
            acc_h8(a00, a01, sv, 1.0f);
            int e0 = offs[node], e1 = offs[node + 1];
            int e = e0;
            for (; e + 4 <= e1; e += 4) {
                int i0 = csr[e], i1 = csr[e + 1], i2 = csr[e + 2], i3 = csr[e + 3];
                H8 v0 = *(const H8*)&xp[(size_t)i0 * 32 + f0];
                H8 v1 = *(const H8*)&xp[(size_t)i1 * 32 + f0];
                H8 v2 = *(const H8*)&xp[(size_t)i2 * 32 + f0];
                H8 v3 = *(const H8*)&xp[(size_t)i3 * 32 + f0];
                acc_h8(a00, a01, v0, 1.0f);
                acc_h8(a10, a11, v1, 1.0f);
                acc_h8(a20, a21, v2, 1.0f);
                acc_h8(a30, a31, v3, 1.0f);
            }
            for (; e < e1; ++e) {
                H8 v = *(const H8*)&xp[(size_t)csr[e] * 32 + f0];
                acc_h8(a00, a01, v, 1.0f);
            }
        }
        float4 A0 = add4(add4(a00, a10), add4(a20, a30));
        float4 A1 = add4(add4(a01, a11), add4(a21, a31));
        A0 = mul4s(A0, dv);
        A1 = mul4s(A1, dv);
        H8 h;
        h.a = __floats2half2_rn(A0.x, A0.y);
        h.b = __floats2half2_rn(A0.z, A0.w);
        h.c = __floats2half2_rn(A1.x, A1.y);
        h.d = __floats2half2_rn(A1.z, A1.w);
        *(H8*)&Xs[nodeL * XSP + pl * 32 + f0] = h;
    }
    __syncthreads();

    // ---- phase 1: H = relu(Xs@W1 + b1) ----
    const f16x8* P1v = (const f16x8*)P1;
    float b1v[7];
#pragma unroll
    for (int mt = 0; mt < 7; ++mt) {
        int m = mt * 16 + lr;
        b1v[mt] = (m < 100) ? b1[m] : 0.0f;
    }
    {
        int rowL = w * 16 + lr;
        f16x8 a0 = *(const f16x8*)&Xs[rowL * XSP + lg * 8];
        f16x8 a1 = *(const f16x8*)&Xs[rowL * XSP + 32 + lg * 8];
        int hbase = w * 16;
#pragma unroll
        for (int mt = 0; mt < 7; ++mt) {
            f16x8 w0 = P1v[(mt * 2 + 0) * 64 + lane];
            f16x8 w1 = P1v[(mt * 2 + 1) * 64 + lane];
            f32x4 acc = {};
            acc = __builtin_amdgcn_mfma_f32_16x16x32_f16(a0, w0, acc, 0, 0, 0);
            acc = __builtin_amdgcn_mfma_f32_16x16x32_f16(a1, w1, acc, 0, 0, 0);
            int col = mt * 16 + lr;
#pragma unroll
            for (int i = 0; i < 4; ++i) {
                int rloc = hbase + lg * 4 + i;
                Hs[rloc * HPS + col] = (_Float16)fmaxf(acc[i] + b1v[mt], 0.0f);
            }
        }
    }
    __syncthreads();   // phase1 Xs reads complete; Xs is dead from here

    // ---- phase 2: D = (Hs@W2) * dinv -> stage in Xs -> planar full-line stream-out ----
    const f16x8* P2v = (const f16x8*)P2;
    int lbase = w * 16;
    const _Float16* hrow = &Hs[(size_t)(lbase + lr) * HPS];
    f16x8 a0 = *(const f16x8*)&hrow[lg * 8];
    f16x8 a1 = *(const f16x8*)&hrow[32 + lg * 8];
    f16x8 a2 = *(const f16x8*)&hrow[64 + lg * 8];
    f16x8 a3 = *(const f16x8*)&hrow[96 + lg * 8];
    float dvq[4];
#pragma unroll
    for (int i = 0; i < 4; ++i) {
        int nd = blockBase + lbase + lg * 4 + i;
        dvq[i] = (nd < n) ? dinv[nd] : 0.0f;
    }
#pragma unroll
    for (int mt = 0; mt < 4; ++mt) {
        f16x8 w0 = P2v[(mt * 4 + 0) * 64 + lane];
        f16x8 w1 = P2v[(mt * 4 + 1) * 64 + lane];
        f16x8 w2 = P2v[(mt * 4 + 2) * 64 + lane];
        f16x8 w3 = P2v[(mt * 4 + 3) * 64 + lane];
        f32x4 acc = {};
        acc = __builtin_amdgcn_mfma_f32_16x16x32_f16(a0, w0, acc, 0, 0, 0);
        acc = __builtin_amdgcn_mfma_f32_16x16x32_f16(a1, w1, acc, 0, 0, 0);
        acc = __builtin_amdgcn_mfma_f32_16x16x32_f16(a2, w2, acc, 0, 0, 0);
        acc = __builtin_amdgcn_mfma_f32_16x16x32_f16(a3, w3, acc, 0, 0, 0);
        int col = mt * 16 + lr;
#pragma unroll
        for (int i = 0; i < 4; ++i)
            Xs[(lbase + lg * 4 + i) * XSP + col] = (_Float16)(acc[i] * dvq[i]);
    }
    __syncthreads();

    // stream out: 64 rows x (32+32) cols, coalesced H8 into planes (no RFO)
    for (int i = tid; i < 64 * 4; i += 256) {
        int r = i >> 2, cc = (i & 3) * 8;
        int nd = blockBase + r;
        if (nd < n) {
            *(H8*)&outA[(size_t)nd * 32 + cc] = *(const H8*)&Xs[r * XSP + cc];
            *(H8*)&outB[(size_t)nd * 32 + cc] = *(const H8*)&Xs[r * XSP + 32 + cc];
        }
    }
}

// ---------------- fused agg2 + gemm3 (MFMA), planar gather, 64-node blocks ----------
constexpr int YP = 72;
__global__ __launch_bounds__(256) void agg2g3(
    const __half* __restrict__ sA, const __half* __restrict__ sB,
    const int* __restrict__ offs, const int* __restrict__ csr,
    const float* __restrict__ dinv,
    const float* __restrict__ b2, const __half* __restrict__ P3,
    __half* __restrict__ out, int n) {
    __shared__ alignas(16) _Float16 Ys[64 * YP];   // 9.2 KB (agg out, then D staging)
    int tid = threadIdx.x, lane = tid & 63, w = tid >> 6;
    int lg = lane >> 4, lr = lane & 15;
    int blockBase = blockIdx.x * 64;

    // ---- phase A: two plane-passes, 4 lanes/node (16B each), 64 nodes/block ----
    int nodeL = tid >> 2;
    int f0 = (tid & 3) * 8;            // cols within plane
    int node = blockBase + nodeL;
#pragma unroll
    for (int pl = 0; pl < 2; ++pl) {
        const __half* sp = pl ? sB : sA;
        int cbase = pl * 32;
        float v[8] = {0.f, 0.f, 0.f, 0.f, 0.f, 0.f, 0.f, 0.f};
        if (node < n) {
            float dv = dinv[node];
            float4 z4 = make_float4(0.f, 0.f, 0.f, 0.f);
            float4 a00 = z4, a01 = z4, a10 = z4, a11 = z4, a20 = z4, a21 = z4, a30 = z4, a31 = z4;
            {
                H8 sv = *(const H8*)&sp[(size_t)node * 32 + f0];
                acc_h8(a00, a01, sv, 1.0f);
            }
            int e0 = offs[node], e1 = offs[node + 1];
            int e = e0;
            for (; e + 4 <= e1; e += 4) {
                int i0 = csr[e], i1 = csr[e + 1], i2 = csr[e + 2], i3 = csr[e + 3];
                H8 v0 = *(const H8*)&sp[(size_t)i0 * 32 + f0];
                H8 v1 = *(const H8*)&sp[(size_t)i1 * 32 + f0];
                H8 v2 = *(const H8*)&sp[(size_t)i2 * 32 + f0];
                H8 v3 = *(const H8*)&sp[(size_t)i3 * 32 + f0];
                acc_h8(a00, a01, v0, 1.0f);
                acc_h8(a10, a11, v1, 1.0f);
                acc_h8(a20, a21, v2, 1.0f);
                acc_h8(a30, a31, v3, 1.0f);
            }
            for (; e < e1; ++e) {
                H8 vv = *(const H8*)&sp[(size_t)csr[e] * 32 + f0];
                acc_h8(a00, a01, vv, 1.0f);
            }
            float4 A0 = add4(add4(a00, a10), add4(a20, a30));
            float4 A1 = add4(add4(a01, a11), add4(a21, a31));
            float vr[8] = {A0.x, A0.y, A0.z, A0.w, A1.x, A1.y, A1.z, A1.w};
#pragma unroll
            for (int i = 0; i < 8; ++i) {
                int col = cbase + f0 + i;
                v[i] = (col < 50) ? fmaxf(dv * vr[i] + b2[col], 0.0f) : 0.0f;
            }
        }
        H8 h;
        h.a = __floats2half2_rn(v[0], v[1]);
        h.b = __floats2half2_rn(v[2], v[3]);
        h.c = __floats2half2_rn(v[4], v[5]);
        h.d = __floats2half2_rn(v[6], v[7]);
        *(H8*)&Ys[nodeL * YP + cbase + f0] = h;
    }
    __syncthreads();

    // ---- phase B: D = (Ys@W3) * dinv; wave w owns rows [w*16, w*16+16), both col-tiles
    const f16x8* P3v = (const f16x8*)P3;
    int rowL = w * 16 + lr;
    f16x8 a0 = *(const f16x8*)&Ys[rowL * YP + lg * 8];
    f16x8 a1 = *(const f16x8*)&Ys[rowL * YP + 32 + lg * 8];
    f32x4 acc0 = {}, acc1 = {};
    acc0 = __builtin_amdgcn_mfma_f32_16x16x32_f16(a0, P3v[0 * 64 + lane], acc0, 0, 0, 0);
    acc0 = __builtin_amdgcn_mfma_f32_16x16x32_f16(a1, P3v[1 * 64 + lane], acc0, 0, 0, 0);
    acc1 = __builtin_amdgcn_mfma_f32_16x16x32_f16(a0, P3v[2 * 64 + lane], acc1, 0, 0, 0);
    acc1 = __builtin_amdgcn_mfma_f32_16x16x32_f16(a1, P3v[3 * 64 + lane], acc1, 0, 0, 0);
    __syncthreads();   // all Ys reads complete before D overwrites it
#pragma unroll
    for (int i = 0; i < 4; ++i) {
        int rl = w * 16 + lg * 4 + i;
        int nd = blockBase + rl;
        float dv = (nd < n) ? dinv[nd] : 0.0f;
        Ys[rl * YP + lr]      = (_Float16)(acc0[i] * dv);
        Ys[rl * YP + 16 + lr] = (_Float16)(acc1[i] * dv);
    }
    __syncthreads();

    // stream out: 64 rows x 64B, coalesced H8 (full-line pairs, no RFO)
    for (int i = tid; i < 64 * 4; i += 256) {
        int r = i >> 2, cc = (i & 3) * 8;
        int nd = blockBase + r;
        if (nd < n)
            *(H8*)&out[(size_t)nd * 32 + cc] = *(const H8*)&Ys[r * YP + cc];
    }
}

// ---------------- agg3 (fp16 gather, 1 line/row) + MLP head ----------------
__global__ __launch_bounds__(256) void agg3_mlp_h(
    const __half* __restrict__ s, const int* __restrict__ offs,
    const int* __restrict__ csr, const float* __restrict__ dinv,
    const float* __restrict__ bg,
    const float* __restrict__ Wl1, const float* __restrict__ bl1,
    const float* __restrict__ Wl2, const float* __restrict__ bl2,
    const float* __restrict__ Wl3, const float* __restrict__ bl3,
    float* __restrict__ out, int n) {
    constexpr int LPN = 4;
    __shared__ float W1s[625], W2s[250], W3s[10], b1s[25], b2s[10];
    __shared__ float accs[64 * 26];
    __shared__ float b3s;

    for (int i = threadIdx.x; i < 625; i += 256) W1s[i] = Wl1[i];
    for (int i = threadIdx.x; i < 250; i += 256) W2s[i] = Wl2[i];
    if (threadIdx.x < 10) { W3s[threadIdx.x] = Wl3[threadIdx.x]; b2s[threadIdx.x] = bl2[threadIdx.x]; }
    if (threadIdx.x < 25) b1s[threadIdx.x] = bl1[threadIdx.x];
    if (threadIdx.x == 0) b3s = bl3[0];

    int lane = threadIdx.x % LPN;
    int nl   = threadIdx.x / LPN;
    int node = blockIdx.x * 64 + nl;
    int f0 = lane * 8;

    if (node < n && f0 < 25) {
        float dv = dinv[node];
        float4 z4 = make_float4(0.f, 0.f, 0.f, 0.f);
        float4 a00 = z4, a01 = z4, a10 = z4, a11 = z4, a20 = z4, a21 = z4, a30 = z4, a31 = z4;
        {
            H8 sv = *(const H8*)&s[(size_t)node * 32 + f0];
            acc_h8(a00, a01, sv, 1.0f);
        }
        int e0 = offs[node], e1 = offs[node + 1];
        int e = e0;
        for (; e + 4 <= e1; e += 4) {
            int i0 = csr[e], i1 = csr[e + 1], i2 = csr[e + 2], i3 = csr[e + 3];
            H8 v0 = *(const H8*)&s[(size_t)i0 * 32 + f0];
            H8 v1 = *(const H8*)&s[(size_t)i1 * 32 + f0];
            H8 v2 = *(const H8*)&s[(size_t)i2 * 32 + f0];
            H8 v3 = *(const H8*)&s[(size_t)i3 * 32 + f0];
            acc_h8(a00, a01, v0, 1.0f);
            acc_h8(a10, a11, v1, 1.0f);
            acc_h8(a20, a21, v2, 1.0f);
            acc_h8(a30, a31, v3, 1.0f);
        }
        for (; e < e1; ++e) {
            H8 v = *(const H8*)&s[(size_t)csr[e] * 32 + f0];
            acc_h8(a00, a01, v, 1.0f);
        }
        float4 A0 = add4(add4(a00, a10), add4(a20, a30));
        float4 A1 = add4(add4(a01, a11), add4(a21, a31));
        float v[8] = {A0.x, A0.y, A0.z, A0.w, A1.x, A1.y, A1.z, A1.w};
#pragma unroll
        for (int i = 0; i < 8; ++i)
            if (f0 + i < 25)
                accs[nl * 26 + f0 + i] = fmaxf(dv * v[i] + bg[f0 + i], 0.0f);
    }
    __syncthreads();

    if (threadIdx.x < 64) {
        int nd = blockIdx.x * 64 + threadIdx.x;
        if (nd < n) {
            const float* xr = &accs[threadIdx.x * 26];
            float h1[25];
#pragma unroll
            for (int m = 0; m < 25; ++m) {
                float a = b1s[m];
#pragma unroll
                for (int k = 0; k < 25; ++k) a = fmaf(xr[k], W1s[k * 25 + m], a);
                h1[m] = fmaxf(a, 0.0f);
            }
            float h2[10];
#pragma unroll
            for (int m = 0; m < 10; ++m) {
                float a = b2s[m];
#pragma unroll
                for (int k = 0; k < 25; ++k) a = fmaf(h1[k], W2s[k * 10 + m], a);
                h2[m] = fmaxf(a, 0.0f);
            }
            float a = b3s;
#pragma unroll
            for (int k = 0; k < 10; ++k) a = fmaf(h2[k], W3s[k], a);
            out[nd] = fmaxf(a, 0.0f);
        }
    }
}

// ---------------- launch ----------------

extern "C" void kernel_launch(void* const* d_in, const int* in_sizes, int n_in,
                              void* d_out, int out_size, void* d_ws, size_t ws_size,
                              hipStream_t stream) {
    const float* x0  = (const float*)d_in[0];
    const float* W1  = (const float*)d_in[1];
    const float* b1  = (const float*)d_in[2];
    const float* W2  = (const float*)d_in[3];
    const float* b2  = (const float*)d_in[4];
    const float* W3  = (const float*)d_in[5];
    const float* b3  = (const float*)d_in[6];
    const float* Wl1 = (const float*)d_in[7];
    const float* bl1 = (const float*)d_in[8];
    const float* Wl2 = (const float*)d_in[9];
    const float* bl2 = (const float*)d_in[10];
    const float* Wl3 = (const float*)d_in[11];
    const float* bl3 = (const float*)d_in[12];
    const int*   edge = (const int*)d_in[13];

    int n  = in_sizes[0] / 64;      // 100000
    int ne = in_sizes[13] / 2;      // 1000000
    const int* esrc = edge;
    const int* edst = edge + ne;

    char* ws = (char*)d_ws;
    auto alloc = [&](size_t bytes) {
        char* p = ws;
        ws += (bytes + 255) & ~(size_t)255;
        return p;
    };
    int*    offs       = (int*)alloc((size_t)(n + 1) * 4);
    int*    bucketCur  = (int*)alloc(NBUCK * 4);
    int*    csr        = (int*)alloc((size_t)ne * 4);
    float*  dinv       = (float*)alloc((size_t)n * 4);
    __half* x0hA       = (__half*)alloc((size_t)n * 32 * 2);   // fp16 plane A (cols 0-31)
    __half* x0hB       = (__half*)alloc((size_t)n * 32 * 2);   // fp16 plane B (cols 32-63)
    __half* bufDhA     = (__half*)alloc((size_t)n * 32 * 2);   // gemm12 out plane A
    __half* bufDhB     = (__half*)alloc((size_t)n * 32 * 2);   // gemm12 out plane B
    __half* bufCh      = (__half*)alloc((size_t)n * 32 * 2);   // fp16 s32h (agg2g3 out)
    __half* P1         = (__half*)alloc(7 * 2 * 64 * 8 * 2);   // packed W1 frags
    __half* P2         = (__half*)alloc(4 * 4 * 64 * 8 * 2);   // packed W2 frags
    __half* P3         = (__half*)alloc(2 * 2 * 64 * 8 * 2);   // packed W3 frags
    // pairs (6.29MB) aliases bufDhA (6.4MB): consumed by bucket_csr_scan before gemm12 writes
    int*    pairs = (int*)bufDhA;
    (void)ws_size; (void)n_in; (void)out_size;

    int nbuckets = (n + (1 << BSHIFT) - 1) >> BSHIFT;   // 196
    int nchunk   = (ne + 256 * EPT - 1) / (256 * EPT);  // 245

    // CSR + dinv + weight pack (memset + 2 dispatches)
    hipMemsetAsync(bucketCur, 0, NBUCK * 4, stream);
    partition_pack<<<nchunk + 1, 256, 0, stream>>>(
        esrc, edst, bucketCur, pairs, ne, nchunk, W1, W2, W3, P1, P2, P3);
    bucket_csr_scan<<<nbuckets, 256, 0, stream>>>(
        pairs, bucketCur, offs, dinv, csr, n, ne, nbuckets);

    // x0h planes = fp16(dinv * x0)
    cvt_scale_planar<<<(n * 16 + 255) / 256, 256, 0, stream>>>(x0, dinv, x0hA, x0hB, n * 16);

    // agg1 + gemm1 + gemm2 fused (planar gather + planar out)
    agg1gemm12<<<(n + 63) / 64, 256, 0, stream>>>(
        x0hA, x0hB, offs, csr, dinv, P1, b1, P2, bufDhA, bufDhB, n);

    // agg2 + gemm3 fused (planar gather): bufCh s32h
    agg2g3<<<(n + 63) / 64, 256, 0, stream>>>(
        bufDhA, bufDhB, offs, csr, dinv, b2, P3, bufCh, n);

    // agg3 + MLP head -> d_out
    agg3_mlp_h<<<(n + 63) / 64, 256, 0, stream>>>(
        bufCh, offs, csr, dinv, b3, Wl1, bl1, Wl2, bl2, Wl3, bl3, (float*)d_out, n);
}

// Round 11
// 227.645 us; speedup vs baseline: 1.0638x; 1.0638x over previous
//
#include <hip/hip_runtime.h>
#include <hip/hip_fp16.h>
#include <cstdint>

constexpr int BSHIFT = 9;               // 512 nodes per bucket
constexpr int NBUCK  = 256;             // max buckets (covers 131072 nodes)
constexpr int BUCKET_CAP = 6144;        // slot capacity; E/bucket ~ Poisson(5102), 14 sigma
constexpr int BN = 1 << BSHIFT;         // 512

struct alignas(16) H8 { __half2 a, b, c, d; };
struct alignas(8)  H4 { __half2 a, b; };

typedef _Float16 f16x8 __attribute__((ext_vector_type(8)));
typedef float    f32x4 __attribute__((ext_vector_type(4)));

__device__ __forceinline__ float4 add4(float4 a, float4 b) {
    return make_float4(a.x + b.x, a.y + b.y, a.z + b.z, a.w + b.w);
}
__device__ __forceinline__ float4 mul4s(float4 a, float s) {
    return make_float4(a.x * s, a.y * s, a.z * s, a.w * s);
}
__device__ __forceinline__ void acc_h8(float4& A0, float4& A1, const H8 v, float s) {
    float2 f0 = __half22float2(v.a), f1 = __half22float2(v.b);
    float2 f2 = __half22float2(v.c), f3 = __half22float2(v.d);
    A0.x = fmaf(f0.x, s, A0.x); A0.y = fmaf(f0.y, s, A0.y);
    A0.z = fmaf(f1.x, s, A0.z); A0.w = fmaf(f1.y, s, A0.w);
    A1.x = fmaf(f2.x, s, A1.x); A1.y = fmaf(f2.y, s, A1.y);
    A1.z = fmaf(f3.x, s, A1.z); A1.w = fmaf(f3.y, s, A1.w);
}

// ---------------- partition_edges + weight-frag pack (merged) ----------------
// Fragment layout (mfma_f32_16x16x32_f16, B operand): lane l holds
// B[k = kf*32 + (l>>4)*8 + j][m = mt*16 + (l&15)], j=0..7 contiguous.

constexpr int EPT = 16;  // edges per thread; chunk = 4096
__global__ __launch_bounds__(256) void partition_pack(
    const int* __restrict__ src, const int* __restrict__ dst,
    int* __restrict__ bucketCur, int* __restrict__ pairs, int ne, int nEdgeBlocks,
    const float* __restrict__ W1, const float* __restrict__ W2,
    const float* __restrict__ W3,
    __half* __restrict__ P1, __half* __restrict__ P2, __half* __restrict__ P3) {
    if (blockIdx.x == (unsigned)nEdgeBlocks) {
        int t = threadIdx.x;
        for (int i = t; i < 7 * 2 * 64 * 8; i += 256) {      // W1 [64x100] -> 7mt x 2kf
            int j = i & 7, lane = (i >> 3) & 63, f = i >> 9;
            int mt = f >> 1, kf = f & 1;
            int k = kf * 32 + (lane >> 4) * 8 + j;
            int m = mt * 16 + (lane & 15);
            P1[i] = __float2half_rn(m < 100 ? W1[k * 100 + m] : 0.0f);
        }
        for (int i = t; i < 4 * 4 * 64 * 8; i += 256) {      // W2 [100x50] -> [128x64]
            int j = i & 7, lane = (i >> 3) & 63, f = i >> 9;
            int mt = f >> 2, kf = f & 3;
            int k = kf * 32 + (lane >> 4) * 8 + j;
            int m = mt * 16 + (lane & 15);
            P2[i] = __float2half_rn((k < 100 && m < 50) ? W2[k * 50 + m] : 0.0f);
        }
        for (int i = t; i < 2 * 2 * 64 * 8; i += 256) {      // W3 [50x25] -> [64x32]
            int j = i & 7, lane = (i >> 3) & 63, f = i >> 9;
            int mt = f >> 1, kf = f & 1;
            int k = kf * 32 + (lane >> 4) * 8 + j;
            int m = mt * 16 + (lane & 15);
            P3[i] = __float2half_rn((k < 50 && m < 25) ? W3[k * 25 + m] : 0.0f);
        }
        return;
    }
    __shared__ int lcnt[NBUCK];
    __shared__ int lbase[NBUCK];
    int base = blockIdx.x * (256 * EPT);
    if (threadIdx.x < NBUCK) lcnt[threadIdx.x] = 0;
    __syncthreads();
    int2 ed[EPT];
    int  rnk[EPT];
#pragma unroll
    for (int j = 0; j < EPT; ++j) {
        int e = base + j * 256 + threadIdx.x;
        if (e < ne) {
            int d = dst[e];
            ed[j] = make_int2(src[e], d);
            rnk[j] = atomicAdd(&lcnt[d >> BSHIFT], 1);
        } else {
            ed[j].y = -1;
        }
    }
    __syncthreads();
    if (threadIdx.x < NBUCK) {
        int c = lcnt[threadIdx.x];
        lbase[threadIdx.x] = c ? atomicAdd(&bucketCur[threadIdx.x], c) : 0;
    }
    __syncthreads();
#pragma unroll
    for (int j = 0; j < EPT; ++j) {
        if (ed[j].y >= 0) {
            int b = ed[j].y >> BSHIFT;
            int p = lbase[b] + rnk[j];
            if (p < BUCKET_CAP)
                pairs[(size_t)b * BUCKET_CAP + p] =
                    (ed[j].x << BSHIFT) | (ed[j].y & (BN - 1));
        }
    }
}

// ---------------- bucket_csr with internal bucket-base scan (R3-proven) ----------------
__global__ __launch_bounds__(256) void bucket_csr_scan(
    const int* __restrict__ pairs, const int* __restrict__ bucketCnt,
    int* __restrict__ offs, float* __restrict__ dinv, int* __restrict__ csr,
    int n, int ne, int nbuckets) {
    __shared__ int hist[BN];
    __shared__ int cur[BN];
    __shared__ int tmp[256];
    __shared__ int baseS;
    int b = blockIdx.x;
    int t = threadIdx.x;

    int c = (t < (unsigned)nbuckets) ? bucketCnt[t] : 0;
    tmp[t] = c;
    __syncthreads();
    for (int off = 1; off < 256; off <<= 1) {
        int v = (t >= (unsigned)off) ? tmp[t - off] : 0;
        __syncthreads();
        tmp[t] += v;
        __syncthreads();
    }
    if (t == 0) {
        baseS = b ? tmp[b - 1] : 0;
        if (b == 0) offs[n] = ne;
    }
    __syncthreads();
    int base = baseS;
    int cnt  = bucketCnt[b];
    const int* pb = pairs + (size_t)b * BUCKET_CAP;
    int nodeLo = b << BSHIFT;

    hist[t] = 0;
    hist[t + 256] = 0;
    __syncthreads();
    for (int e = t; e < cnt; e += 256)
        atomicAdd(&hist[pb[e] & (BN - 1)], 1);
    __syncthreads();

    int l0 = 2 * t, l1 = l0 + 1;
    int h0 = hist[l0], h1 = hist[l1];
    tmp[t] = h0 + h1;
    __syncthreads();
    for (int off = 1; off < 256; off <<= 1) {
        int v = (t >= (unsigned)off) ? tmp[t - off] : 0;
        __syncthreads();
        tmp[t] += v;
        __syncthreads();
    }
    int e0 = tmp[t] - (h0 + h1);
    int e1 = e0 + h0;
    int g0 = nodeLo + l0, g1 = nodeLo + l1;
    if (g0 < n) { offs[g0] = base + e0; dinv[g0] = rsqrtf((float)(h0 + 1)); }
    if (g1 < n) { offs[g1] = base + e1; dinv[g1] = rsqrtf((float)(h1 + 1)); }
    cur[l0] = e0;
    cur[l1] = e1;
    __syncthreads();

    for (int e = t; e < cnt; e += 256) {
        int p = pb[e];
        int pos = atomicAdd(&cur[p & (BN - 1)], 1);
        csr[base + pos] = ((unsigned)p) >> BSHIFT;
    }
}

// ---------------- fp32 -> fp16 streaming convert, prescaled by dinv ----------------
__global__ void cvt_scale_f32_f16(const float* __restrict__ x, const float* __restrict__ dinv,
                                  __half* __restrict__ o, int n4) {
    int i = blockIdx.x * blockDim.x + threadIdx.x;
    if (i < n4) {
        float dv = dinv[i >> 4];          // 16 float4 per 64-wide row
        float4 v = ((const float4*)x)[i];
        H4 h;
        h.a = __floats2half2_rn(v.x * dv, v.y * dv);
        h.b = __floats2half2_rn(v.z * dv, v.w * dv);
        ((H4*)o)[i] = h;
    }
}

// ---------------- fused agg1 + gemm1 + gemm2 (MFMA) ----------------
// Block = 64 nodes, 4 waves, wave w owns nodes [w*16, w*16+16).
// Epilogue routes D through dead Xs and streams FULL-LINE H8 rows (no RFO,
// no 2B partial-line stores polluting L2 during the BW-critical gather phase).
constexpr int XSP = 72;   // Xs row stride, halves (144B = 16B-aligned)
constexpr int HPS = 136;  // Hs row stride, halves (272B = 16B-aligned)
__global__ __launch_bounds__(256, 4) void agg1gemm12(
    const __half* __restrict__ x, const int* __restrict__ offs,
    const int* __restrict__ csr, const float* __restrict__ dinv,
    const __half* __restrict__ P1, const float* __restrict__ b1,
    const __half* __restrict__ P2, __half* __restrict__ out, int n) {
    __shared__ alignas(16) _Float16 Xs[64 * XSP];   // 9.2 KB (agg out, then D staging)
    __shared__ alignas(16) _Float16 Hs[64 * HPS];   // 17.4 KB
    int tid = threadIdx.x, lane = tid & 63, w = tid >> 6;
    int lg = lane >> 4, lr = lane & 15;
    int blockBase = blockIdx.x * 64;

    // zero Hs pad cols 112..127 (read by W2 kfrag3; must be finite)
    for (int i = tid; i < 64 * 2; i += 256) {
        f16x8 zz = {};
        *(f16x8*)&Hs[(i >> 1) * HPS + 112 + (i & 1) * 8] = zz;
    }

    // ---- phase 0: aggregate 16 nodes/wave (2 passes of 8) ----
    int f0 = (lane & 7) * 8;
#pragma unroll
    for (int p = 0; p < 2; ++p) {
        int nl = w * 16 + p * 8 + (lane >> 3);
        int node = blockBase + nl;
        float4 z4 = make_float4(0.f, 0.f, 0.f, 0.f);
        float4 a00 = z4, a01 = z4, a10 = z4, a11 = z4, a20 = z4, a21 = z4, a30 = z4, a31 = z4;
        float dv = 0.0f;
        if (node < n) {
            dv = dinv[node];
            H8 sv = *(const H8*)&x[(size_t)node * 64 + f0];   // self term (prescaled)
            acc_h8(a00, a01, sv, 1.0f);
            int e0 = offs[node], e1 = offs[node + 1];
            int e = e0;
            for (; e + 4 <= e1; e += 4) {
                int i0 = csr[e], i1 = csr[e + 1], i2 = csr[e + 2], i3 = csr[e + 3];
                H8 v0 = *(const H8*)&x[(size_t)i0 * 64 + f0];
                H8 v1 = *(const H8*)&x[(size_t)i1 * 64 + f0];
                H8 v2 = *(const H8*)&x[(size_t)i2 * 64 + f0];
                H8 v3 = *(const H8*)&x[(size_t)i3 * 64 + f0];
                acc_h8(a00, a01, v0, 1.0f);
                acc_h8(a10, a11, v1, 1.0f);
                acc_h8(a20, a21, v2, 1.0f);
                acc_h8(a30, a31, v3, 1.0f);
            }
            for (; e < e1; ++e) {
                H8 v = *(const H8*)&x[(size_t)csr[e] * 64 + f0];
                acc_h8(a00, a01, v, 1.0f);
            }
        }
        float4 A0 = add4(add4(a00, a10), add4(a20, a30));
        float4 A1 = add4(add4(a01, a11), add4(a21, a31));
        A0 = mul4s(A0, dv);
        A1 = mul4s(A1, dv);
        H8 h;
        h.a = __floats2half2_rn(A0.x, A0.y);
        h.b = __floats2half2_rn(A0.z, A0.w);
        h.c = __floats2half2_rn(A1.x, A1.y);
        h.d = __floats2half2_rn(A1.z, A1.w);
        *(H8*)&Xs[nl * XSP + f0] = h;
    }
    __syncthreads();

    // ---- phase 1: H = relu(Xs@W1 + b1) ----
    const f16x8* P1v = (const f16x8*)P1;
    float b1v[7];
#pragma unroll
    for (int mt = 0; mt < 7; ++mt) {
        int m = mt * 16 + lr;
        b1v[mt] = (m < 100) ? b1[m] : 0.0f;
    }
    {
        int rowL = w * 16 + lr;
        f16x8 a0 = *(const f16x8*)&Xs[rowL * XSP + lg * 8];
        f16x8 a1 = *(const f16x8*)&Xs[rowL * XSP + 32 + lg * 8];
        int hbase = w * 16;
#pragma unroll
        for (int mt = 0; mt < 7; ++mt) {
            f16x8 w0 = P1v[(mt * 2 + 0) * 64 + lane];
            f16x8 w1 = P1v[(mt * 2 + 1) * 64 + lane];
            f32x4 acc = {};
            acc = __builtin_amdgcn_mfma_f32_16x16x32_f16(a0, w0, acc, 0, 0, 0);
            acc = __builtin_amdgcn_mfma_f32_16x16x32_f16(a1, w1, acc, 0, 0, 0);
            int col = mt * 16 + lr;
#pragma unroll
            for (int i = 0; i < 4; ++i) {
                int rloc = hbase + lg * 4 + i;
                Hs[rloc * HPS + col] = (_Float16)fmaxf(acc[i] + b1v[mt], 0.0f);
            }
        }
    }
    __syncthreads();   // phase1 Xs reads complete; Xs is dead from here

    // ---- phase 2: D = (Hs@W2) * dinv -> stage in Xs -> full-line stream-out ----
    const f16x8* P2v = (const f16x8*)P2;
    int lbase = w * 16;
    const _Float16* hrow = &Hs[(size_t)(lbase + lr) * HPS];
    f16x8 a0 = *(const f16x8*)&hrow[lg * 8];
    f16x8 a1 = *(const f16x8*)&hrow[32 + lg * 8];
    f16x8 a2 = *(const f16x8*)&hrow[64 + lg * 8];
    f16x8 a3 = *(const f16x8*)&hrow[96 + lg * 8];
    float dvq[4];
#pragma unroll
    for (int i = 0; i < 4; ++i) {
        int node = blockBase + lbase + lg * 4 + i;
        dvq[i] = (node < n) ? dinv[node] : 0.0f;
    }
#pragma unroll
    for (int mt = 0; mt < 4; ++mt) {
        f16x8 w0 = P2v[(mt * 4 + 0) * 64 + lane];
        f16x8 w1 = P2v[(mt * 4 + 1) * 64 + lane];
        f16x8 w2 = P2v[(mt * 4 + 2) * 64 + lane];
        f16x8 w3 = P2v[(mt * 4 + 3) * 64 + lane];
        f32x4 acc = {};
        acc = __builtin_amdgcn_mfma_f32_16x16x32_f16(a0, w0, acc, 0, 0, 0);
        acc = __builtin_amdgcn_mfma_f32_16x16x32_f16(a1, w1, acc, 0, 0, 0);
        acc = __builtin_amdgcn_mfma_f32_16x16x32_f16(a2, w2, acc, 0, 0, 0);
        acc = __builtin_amdgcn_mfma_f32_16x16x32_f16(a3, w3, acc, 0, 0, 0);
        int col = mt * 16 + lr;
#pragma unroll
        for (int i = 0; i < 4; ++i)
            Xs[(lbase + lg * 4 + i) * XSP + col] = (_Float16)(acc[i] * dvq[i]);
    }
    __syncthreads();

    // stream out: 64 rows x 128B, coalesced H8 (full-line, no RFO)
    for (int i = tid; i < 64 * 8; i += 256) {
        int r = i >> 3, cc = (i & 7) * 8;
        int node = blockBase + r;
        if (node < n)
            *(H8*)&out[(size_t)node * 64 + cc] = *(const H8*)&Xs[r * XSP + cc];
    }
}

// ---------------- fused agg2 + gemm3 (MFMA), full-line epilogue via Ys ----------------
constexpr int YP = 72;
__global__ __launch_bounds__(256) void agg2g3(
    const __half* __restrict__ s, const int* __restrict__ offs,
    const int* __restrict__ csr, const float* __restrict__ dinv,
    const float* __restrict__ b2, const __half* __restrict__ P3,
    __half* __restrict__ out, int n) {
    __shared__ alignas(16) _Float16 Ys[32 * YP];   // 4.6 KB (agg out, then D staging)
    int tid = threadIdx.x, lane = tid & 63, w = tid >> 6;
    int lg = lane >> 4, lr = lane & 15;
    int blockBase = blockIdx.x * 32;

    // ---- phase A: aggregate (8 lanes per node; lane7 pure pad) ----
    int nodeL = tid >> 3;
    int f0 = (tid & 7) * 8;
    int node = blockBase + nodeL;
    float v[8] = {0.f, 0.f, 0.f, 0.f, 0.f, 0.f, 0.f, 0.f};
    if (node < n && f0 < 56) {
        float dv = dinv[node];
        float4 z4 = make_float4(0.f, 0.f, 0.f, 0.f);
        float4 a00 = z4, a01 = z4, a10 = z4, a11 = z4, a20 = z4, a21 = z4, a30 = z4, a31 = z4;
        {
            H8 sv = *(const H8*)&s[(size_t)node * 64 + f0];
            acc_h8(a00, a01, sv, 1.0f);
        }
        int e0 = offs[node], e1 = offs[node + 1];
        int e = e0;
        for (; e + 4 <= e1; e += 4) {
            int i0 = csr[e], i1 = csr[e + 1], i2 = csr[e + 2], i3 = csr[e + 3];
            H8 v0 = *(const H8*)&s[(size_t)i0 * 64 + f0];
            H8 v1 = *(const H8*)&s[(size_t)i1 * 64 + f0];
            H8 v2 = *(const H8*)&s[(size_t)i2 * 64 + f0];
            H8 v3 = *(const H8*)&s[(size_t)i3 * 64 + f0];
            acc_h8(a00, a01, v0, 1.0f);
            acc_h8(a10, a11, v1, 1.0f);
            acc_h8(a20, a21, v2, 1.0f);
            acc_h8(a30, a31, v3, 1.0f);
        }
        for (; e < e1; ++e) {
            H8 vv = *(const H8*)&s[(size_t)csr[e] * 64 + f0];
            acc_h8(a00, a01, vv, 1.0f);
        }
        float4 A0 = add4(add4(a00, a10), add4(a20, a30));
        float4 A1 = add4(add4(a01, a11), add4(a21, a31));
        float vr[8] = {A0.x, A0.y, A0.z, A0.w, A1.x, A1.y, A1.z, A1.w};
#pragma unroll
        for (int i = 0; i < 8; ++i)
            v[i] = (f0 + i < 50) ? fmaxf(dv * vr[i] + b2[f0 + i], 0.0f) : 0.0f;
    }
    {
        H8 h;
        h.a = __floats2half2_rn(v[0], v[1]);
        h.b = __floats2half2_rn(v[2], v[3]);
        h.c = __floats2half2_rn(v[4], v[5]);
        h.d = __floats2half2_rn(v[6], v[7]);
        *(H8*)&Ys[nodeL * YP + f0] = h;
    }
    __syncthreads();

    // ---- phase B: D = (Ys@W3) * dinv -> stage in Ys -> full-line stream-out ----
    int rt = w >> 1, mt = w & 1;
    const f16x8* P3v = (const f16x8*)P3;
    f16x8 w0 = P3v[(mt * 2 + 0) * 64 + lane];
    f16x8 w1 = P3v[(mt * 2 + 1) * 64 + lane];
    int rowL = rt * 16 + lr;
    f16x8 a0 = *(const f16x8*)&Ys[rowL * YP + lg * 8];
    f16x8 a1 = *(const f16x8*)&Ys[rowL * YP + 32 + lg * 8];
    f32x4 acc = {};
    acc = __builtin_amdgcn_mfma_f32_16x16x32_f16(a0, w0, acc, 0, 0, 0);
    acc = __builtin_amdgcn_mfma_f32_16x16x32_f16(a1, w1, acc, 0, 0, 0);
    __syncthreads();   // all Ys reads complete before D overwrites it
    int col = mt * 16 + lr;
#pragma unroll
    for (int i = 0; i < 4; ++i) {
        int rl = rt * 16 + lg * 4 + i;
        int nd = blockBase + rl;
        float dv = (nd < n) ? dinv[nd] : 0.0f;
        Ys[rl * YP + col] = (_Float16)(acc[i] * dv);
    }
    __syncthreads();

    // stream out: 32 rows x 64B, coalesced H8 (full-line pairs, no RFO)
    if (tid < 128) {
        int r = tid >> 2, cc = (tid & 3) * 8;
        int nd = blockBase + r;
        if (nd < n)
            *(H8*)&out[(size_t)nd * 32 + cc] = *(const H8*)&Ys[r * YP + cc];
    }
}

// ---------------- agg3 (fp16 gather, 1 line/row) + MLP head ----------------
__global__ __launch_bounds__(256) void agg3_mlp_h(
    const __half* __restrict__ s, const int* __restrict__ offs,
    const int* __restrict__ csr, const float* __restrict__ dinv,
    const float* __restrict__ bg,
    const float* __restrict__ Wl1, const float* __restrict__ bl1,
    const float* __restrict__ Wl2, const float* __restrict__ bl2,
    const float* __restrict__ Wl3, const float* __restrict__ bl3,
    float* __restrict__ out, int n) {
    constexpr int LPN = 4;
    __shared__ float W1s[625], W2s[250], W3s[10], b1s[25], b2s[10];
    __shared__ float accs[64 * 26];
    __shared__ float b3s;

    for (int i = threadIdx.x; i < 625; i += 256) W1s[i] = Wl1[i];
    for (int i = threadIdx.x; i < 250; i += 256) W2s[i] = Wl2[i];
    if (threadIdx.x < 10) { W3s[threadIdx.x] = Wl3[threadIdx.x]; b2s[threadIdx.x] = bl2[threadIdx.x]; }
    if (threadIdx.x < 25) b1s[threadIdx.x] = bl1[threadIdx.x];
    if (threadIdx.x == 0) b3s = bl3[0];

    int lane = threadIdx.x % LPN;
    int nl   = threadIdx.x / LPN;
    int node = blockIdx.x * 64 + nl;
    int f0 = lane * 8;

    if (node < n && f0 < 25) {
        float dv = dinv[node];
        float4 z4 = make_float4(0.f, 0.f, 0.f, 0.f);
        float4 a00 = z4, a01 = z4, a10 = z4, a11 = z4, a20 = z4, a21 = z4, a30 = z4, a31 = z4;
        {
            H8 sv = *(const H8*)&s[(size_t)node * 32 + f0];
            acc_h8(a00, a01, sv, 1.0f);
        }
        int e0 = offs[node], e1 = offs[node + 1];
        int e = e0;
        for (; e + 4 <= e1; e += 4) {
            int i0 = csr[e], i1 = csr[e + 1], i2 = csr[e + 2], i3 = csr[e + 3];
            H8 v0 = *(const H8*)&s[(size_t)i0 * 32 + f0];
            H8 v1 = *(const H8*)&s[(size_t)i1 * 32 + f0];
            H8 v2 = *(const H8*)&s[(size_t)i2 * 32 + f0];
            H8 v3 = *(const H8*)&s[(size_t)i3 * 32 + f0];
            acc_h8(a00, a01, v0, 1.0f);
            acc_h8(a10, a11, v1, 1.0f);
            acc_h8(a20, a21, v2, 1.0f);
            acc_h8(a30, a31, v3, 1.0f);
        }
        for (; e < e1; ++e) {
            H8 v = *(const H8*)&s[(size_t)csr[e] * 32 + f0];
            acc_h8(a00, a01, v, 1.0f);
        }
        float4 A0 = add4(add4(a00, a10), add4(a20, a30));
        float4 A1 = add4(add4(a01, a11), add4(a21, a31));
        float v[8] = {A0.x, A0.y, A0.z, A0.w, A1.x, A1.y, A1.z, A1.w};
#pragma unroll
        for (int i = 0; i < 8; ++i)
            if (f0 + i < 25)
                accs[nl * 26 + f0 + i] = fmaxf(dv * v[i] + bg[f0 + i], 0.0f);
    }
    __syncthreads();

    if (threadIdx.x < 64) {
        int nd = blockIdx.x * 64 + threadIdx.x;
        if (nd < n) {
            const float* xr = &accs[threadIdx.x * 26];
            float h1[25];
#pragma unroll
            for (int m = 0; m < 25; ++m) {
                float a = b1s[m];
#pragma unroll
                for (int k = 0; k < 25; ++k) a = fmaf(xr[k], W1s[k * 25 + m], a);
                h1[m] = fmaxf(a, 0.0f);
            }
            float h2[10];
#pragma unroll
            for (int m = 0; m < 10; ++m) {
                float a = b2s[m];
#pragma unroll
                for (int k = 0; k < 25; ++k) a = fmaf(h1[k], W2s[k * 10 + m], a);
                h2[m] = fmaxf(a, 0.0f);
            }
            float a = b3s;
#pragma unroll
            for (int k = 0; k < 10; ++k) a = fmaf(h2[k], W3s[k], a);
            out[nd] = fmaxf(a, 0.0f);
        }
    }
}

// ---------------- launch ----------------

extern "C" void kernel_launch(void* const* d_in, const int* in_sizes, int n_in,
                              void* d_out, int out_size, void* d_ws, size_t ws_size,
                              hipStream_t stream) {
    const float* x0  = (const float*)d_in[0];
    const float* W1  = (const float*)d_in[1];
    const float* b1  = (const float*)d_in[2];
    const float* W2  = (const float*)d_in[3];
    const float* b2  = (const float*)d_in[4];
    const float* W3  = (const float*)d_in[5];
    const float* b3  = (const float*)d_in[6];
    const float* Wl1 = (const float*)d_in[7];
    const float* bl1 = (const float*)d_in[8];
    const float* Wl2 = (const float*)d_in[9];
    const float* bl2 = (const float*)d_in[10];
    const float* Wl3 = (const float*)d_in[11];
    const float* bl3 = (const float*)d_in[12];
    const int*   edge = (const int*)d_in[13];

    int n  = in_sizes[0] / 64;      // 100000
    int ne = in_sizes[13] / 2;      // 1000000
    const int* esrc = edge;
    const int* edst = edge + ne;

    char* ws = (char*)d_ws;
    auto alloc = [&](size_t bytes) {
        char* p = ws;
        ws += (bytes + 255) & ~(size_t)255;
        return p;
    };
    int*    offs       = (int*)alloc((size_t)(n + 1) * 4);
    int*    bucketCur  = (int*)alloc(NBUCK * 4);
    int*    csr        = (int*)alloc((size_t)ne * 4);
    float*  dinv       = (float*)alloc((size_t)n * 4);
    __half* x0h        = (__half*)alloc((size_t)n * 64 * 2);   // fp16 s64h (dinv-prescaled)
    __half* bufDh      = (__half*)alloc((size_t)n * 64 * 2);   // fp16 s64h (agg1gemm12 out)
    __half* bufCh      = (__half*)alloc((size_t)n * 32 * 2);   // fp16 s32h (agg2g3 out)
    __half* P1         = (__half*)alloc(7 * 2 * 64 * 8 * 2);   // packed W1 frags
    __half* P2         = (__half*)alloc(4 * 4 * 64 * 8 * 2);   // packed W2 frags
    __half* P3         = (__half*)alloc(2 * 2 * 64 * 8 * 2);   // packed W3 frags
    // pairs (6.3MB) aliases bufDh: consumed by bucket_csr_scan before agg1gemm12 writes it
    int*    pairs = (int*)bufDh;
    (void)ws_size; (void)n_in; (void)out_size;

    int nbuckets = (n + (1 << BSHIFT) - 1) >> BSHIFT;   // 196
    int nchunk   = (ne + 256 * EPT - 1) / (256 * EPT);  // 245

    // CSR + dinv + weight pack (memset + 2 dispatches)
    hipMemsetAsync(bucketCur, 0, NBUCK * 4, stream);
    partition_pack<<<nchunk + 1, 256, 0, stream>>>(
        esrc, edst, bucketCur, pairs, ne, nchunk, W1, W2, W3, P1, P2, P3);
    bucket_csr_scan<<<nbuckets, 256, 0, stream>>>(
        pairs, bucketCur, offs, dinv, csr, n, ne, nbuckets);

    // x0h = fp16(dinv * x0)
    cvt_scale_f32_f16<<<(n * 16 + 255) / 256, 256, 0, stream>>>(x0, dinv, x0h, n * 16);

    // agg1 + gemm1 + gemm2 fused: bufDh = fp16(dinv * (relu(agg(x0h)@W1+b1) @ W2))
    agg1gemm12<<<(n + 63) / 64, 256, 0, stream>>>(
        x0h, offs, csr, dinv, P1, b1, P2, bufDh, n);

    // agg2 + gemm3 fused: bufCh = fp16(dinv * (relu(dinv*agg(bufDh)+b2) @ W3)) s32h
    agg2g3<<<(n + 31) / 32, 256, 0, stream>>>(
        bufDh, offs, csr, dinv, b2, P3, bufCh, n);

    // agg3 + MLP head -> d_out
    agg3_mlp_h<<<(n + 63) / 64, 256, 0, stream>>>(
        bufCh, offs, csr, dinv, b3, Wl1, bl1, Wl2, bl2, Wl3, bl3, (float*)d_out, n);
}